// Round 4
// baseline (2546.874 us; speedup 1.0000x reference)
//
#include <hip/hip_runtime.h>
#include <hip/hip_bf16.h>
#include <math.h>

// dims
constexpr int B_   = 2;
constexpr int L_   = 512;
constexpr int LP1  = 513;
constexpr int D_   = 512;
constexpr int H_   = 8;
constexpr int HD_  = 64;
constexpr int FF_  = 2048;
constexpr int RFFD = 32;
constexpr int RBH  = 64;
constexpr int M_   = B_ * LP1;     // 1026
constexpr float EPS_ = 1e-5f;

// ws layout (floats): z | x1 | qkv   — total 2,626,560 floats = 10.5 MB
constexpr size_t OFFZ   = 0;
constexpr size_t OFFX1  = (size_t)M_ * D_;              // 525,312
constexpr size_t OFFQKV = OFFX1 + (size_t)M_ * D_;      // 1,050,624

__device__ __forceinline__ float gelu_exact(float x) {
    return 0.5f * x * (1.0f + erff(x * 0.70710678118654752f));
}

// ---------------- LN1: one block (256) per token ----------------
__global__ void k_ln(const float* __restrict__ x, const float* __restrict__ g,
                     const float* __restrict__ be, float* __restrict__ out) {
    const int m = blockIdx.x;
    const int t = threadIdx.x;
    __shared__ float red[256];
    const float v0 = x[(size_t)m * D_ + t];
    const float v1 = x[(size_t)m * D_ + t + 256];
    red[t] = v0 + v1;
    __syncthreads();
    for (int off = 128; off > 0; off >>= 1) {
        if (t < off) red[t] += red[t + off];
        __syncthreads();
    }
    const float mu = red[0] * (1.0f / D_);
    __syncthreads();
    const float d0 = v0 - mu, d1 = v1 - mu;
    red[t] = d0 * d0 + d1 * d1;
    __syncthreads();
    for (int off = 128; off > 0; off >>= 1) {
        if (t < off) red[t] += red[t + off];
        __syncthreads();
    }
    const float rstd = rsqrtf(red[0] * (1.0f / D_) + EPS_);
    out[(size_t)m * D_ + t]       = d0 * rstd * g[t]       + be[t];
    out[(size_t)m * D_ + t + 256] = d1 * rstd * g[t + 256] + be[t + 256];
}

// ---------------- qkv = z @ in_w^T + in_b (naive, one thread per output) ----------------
__global__ void k_qkv(const float* __restrict__ z, const float* __restrict__ W,
                      const float* __restrict__ bias, float* __restrict__ qkv) {
    const size_t idx = (size_t)blockIdx.x * 256 + threadIdx.x;
    if (idx >= (size_t)M_ * 3 * D_) return;
    const int m = (int)(idx / (3 * D_));
    const int n = (int)(idx % (3 * D_));
    const float* ip = z + (size_t)m * D_;
    const float* wp = W + (size_t)n * D_;
    float acc = bias[n];
    for (int k = 0; k < D_; ++k) acc += ip[k] * wp[k];
    qkv[idx] = acc;
}

// ---------------- fused attention: bias-MLP + scores + softmax + PV + out-proj + residual
// one block (256) per query token m=(b,i)
__global__ void k_attn(const float* __restrict__ qkv, const float* __restrict__ s_norm,
                       const float* __restrict__ rff, const float* __restrict__ w1,
                       const float* __restrict__ b1, const float* __restrict__ w2,
                       const float* __restrict__ b2, const float* __restrict__ out_w,
                       const float* __restrict__ out_b, const float* __restrict__ x,
                       float* __restrict__ x1) {
    const int m = blockIdx.x;
    const int b = m / LP1;
    const int i = m % LP1;
    const int t = threadIdx.x;
    __shared__ float q_s[D_];
    __shared__ float p_s[H_][LP1 + 3];
    __shared__ float a_s[D_];
    __shared__ float red[256];

    q_s[t]       = qkv[(size_t)m * (3 * D_) + t];
    q_s[t + 256] = qkv[(size_t)m * (3 * D_) + t + 256];
    const float s_i = (i == 0) ? 0.f : s_norm[b * L_ + i - 1];
    __syncthreads();

    // scores for all heads: p_s[h][j] = biasMLP(s_i - s_j)[h] + (q_h . k_h)/8
    for (int j = t; j < LP1; j += 256) {
        const float s_j = (j == 0) ? 0.f : s_norm[b * L_ + j - 1];
        const float ds = s_i - s_j;
        float feat[RFFD];
        #pragma unroll
        for (int k2 = 0; k2 < RFFD; ++k2) feat[k2] = sinf(ds * rff[k2]);
        float bh[H_];
        #pragma unroll
        for (int h = 0; h < H_; ++h) bh[h] = b2[h];
        for (int l = 0; l < RBH; ++l) {
            float acc = b1[l];
            #pragma unroll
            for (int k2 = 0; k2 < RFFD; ++k2) acc += feat[k2] * w1[l * RFFD + k2];
            const float gl = gelu_exact(acc);
            #pragma unroll
            for (int h = 0; h < H_; ++h) bh[h] += gl * w2[h * RBH + l];
        }
        const float* krow = qkv + (size_t)(b * LP1 + j) * (3 * D_) + D_;
        #pragma unroll
        for (int h = 0; h < H_; ++h) {
            float dot = 0.f;
            #pragma unroll
            for (int d = 0; d < HD_; ++d) dot += q_s[h * HD_ + d] * krow[h * HD_ + d];
            p_s[h][j] = bh[h] + 0.125f * dot;
        }
    }
    __syncthreads();

    // softmax per head (block-wide reduction, heads sequential)
    for (int h = 0; h < H_; ++h) {
        float mx = -1e30f;
        for (int j = t; j < LP1; j += 256) mx = fmaxf(mx, p_s[h][j]);
        red[t] = mx;
        __syncthreads();
        for (int off = 128; off > 0; off >>= 1) {
            if (t < off) red[t] = fmaxf(red[t], red[t + off]);
            __syncthreads();
        }
        mx = red[0];
        __syncthreads();
        float sum = 0.f;
        for (int j = t; j < LP1; j += 256) {
            const float e = __expf(p_s[h][j] - mx);
            p_s[h][j] = e;
            sum += e;
        }
        red[t] = sum;
        __syncthreads();
        for (int off = 128; off > 0; off >>= 1) {
            if (t < off) red[t] += red[t + off];
            __syncthreads();
        }
        const float inv = 1.0f / red[0];
        __syncthreads();
        for (int j = t; j < LP1; j += 256) p_s[h][j] *= inv;
        __syncthreads();
    }

    // PV: a[e] = sum_j p[h(e)][j] * v[b,j,e]   (coalesced across threads for fixed j)
    {
        const float* vbase = qkv + (size_t)(b * LP1) * (3 * D_) + 2 * D_;
        for (int e = t; e < D_; e += 256) {
            const int h = e >> 6;
            float acc = 0.f;
            for (int j = 0; j < LP1; ++j) acc += p_s[h][j] * vbase[(size_t)j * (3 * D_) + e];
            a_s[e] = acc;
        }
    }
    __syncthreads();

    // out-proj + residual: x1[m,c] = x[m,c] + out_b[c] + sum_e a[e]*out_w[c,e]
    for (int c = t; c < D_; c += 256) {
        const float* wp = out_w + (size_t)c * D_;
        float acc = out_b[c];
        for (int e = 0; e < D_; ++e) acc += a_s[e] * wp[e];
        x1[(size_t)m * D_ + c] = x[(size_t)m * D_ + c] + acc;
    }
}

// ---------------- fused LN2 + FF1 + GELU + FF2 + residual: one block per token ----------------
__global__ void k_ff(const float* __restrict__ x1, const float* __restrict__ g,
                     const float* __restrict__ be, const float* __restrict__ w1,
                     const float* __restrict__ b1, const float* __restrict__ w2,
                     const float* __restrict__ b2, float* __restrict__ out) {
    const int m = blockIdx.x;
    const int t = threadIdx.x;
    __shared__ float h2[D_];
    __shared__ float hact[FF_];
    __shared__ float red[256];

    const float v0 = x1[(size_t)m * D_ + t];
    const float v1 = x1[(size_t)m * D_ + t + 256];
    red[t] = v0 + v1;
    __syncthreads();
    for (int off = 128; off > 0; off >>= 1) {
        if (t < off) red[t] += red[t + off];
        __syncthreads();
    }
    const float mu = red[0] * (1.0f / D_);
    __syncthreads();
    const float d0 = v0 - mu, d1 = v1 - mu;
    red[t] = d0 * d0 + d1 * d1;
    __syncthreads();
    for (int off = 128; off > 0; off >>= 1) {
        if (t < off) red[t] += red[t + off];
        __syncthreads();
    }
    const float rstd = rsqrtf(red[0] * (1.0f / D_) + EPS_);
    h2[t]       = d0 * rstd * g[t]       + be[t];
    h2[t + 256] = d1 * rstd * g[t + 256] + be[t + 256];
    __syncthreads();

    for (int n = t; n < FF_; n += 256) {
        const float* wp = w1 + (size_t)n * D_;
        float acc = b1[n];
        for (int d = 0; d < D_; ++d) acc += h2[d] * wp[d];
        hact[n] = gelu_exact(acc);
    }
    __syncthreads();

    for (int c = t; c < D_; c += 256) {
        const float* wp = w2 + (size_t)c * FF_;
        float acc = b2[c];
        for (int k2 = 0; k2 < FF_; ++k2) acc += hact[k2] * wp[k2];
        out[(size_t)m * D_ + c] = x1[(size_t)m * D_ + c] + acc;
    }
}

extern "C" void kernel_launch(void* const* d_in, const int* in_sizes, int n_in,
                              void* d_out, int out_size, void* d_ws, size_t ws_size,
                              hipStream_t stream) {
    const float* x      = (const float*)d_in[0];
    const float* s_norm = (const float*)d_in[1];
    const float* rff    = (const float*)d_in[2];
    const float* rb_w1  = (const float*)d_in[3];
    const float* rb_b1  = (const float*)d_in[4];
    const float* rb_w2  = (const float*)d_in[5];
    const float* rb_b2  = (const float*)d_in[6];
    const float* n1_g   = (const float*)d_in[7];
    const float* n1_b   = (const float*)d_in[8];
    const float* n2_g   = (const float*)d_in[9];
    const float* n2_b   = (const float*)d_in[10];
    const float* in_w   = (const float*)d_in[11];
    const float* in_b   = (const float*)d_in[12];
    const float* out_w  = (const float*)d_in[13];
    const float* out_b  = (const float*)d_in[14];
    const float* ff_w1  = (const float*)d_in[15];
    const float* ff_b1  = (const float*)d_in[16];
    const float* ff_w2  = (const float*)d_in[17];
    const float* ff_b2  = (const float*)d_in[18];

    float* ws  = (float*)d_ws;
    float* z   = ws + OFFZ;
    float* x1  = ws + OFFX1;
    float* qkv = ws + OFFQKV;

    // 1) LN1
    k_ln<<<M_, 256, 0, stream>>>(x, n1_g, n1_b, z);
    // 2) qkv projection
    {
        size_t tot = (size_t)M_ * 3 * D_;
        k_qkv<<<(int)((tot + 255) / 256), 256, 0, stream>>>(z, in_w, in_b, qkv);
    }
    // 3) fused attention (bias MLP on the fly) + out-proj + residual
    k_attn<<<M_, 256, 0, stream>>>(qkv, s_norm, rff, rb_w1, rb_b1, rb_w2, rb_b2,
                                   out_w, out_b, x, x1);
    // 4) fused LN2 + FF + residual -> f32 out
    k_ff<<<M_, 256, 0, stream>>>(x1, n2_g, n2_b, ff_w1, ff_b1, ff_w2, ff_b2,
                                 (float*)d_out);
}

// Round 5
// 503.102 us; speedup vs baseline: 5.0623x; 5.0623x over previous
//
#include <hip/hip_runtime.h>
#include <hip/hip_bf16.h>
#include <math.h>

// dims
constexpr int B_   = 2;
constexpr int L_   = 512;
constexpr int LP1  = 513;
constexpr int D_   = 512;
constexpr int H_   = 8;
constexpr int HD_  = 64;
constexpr int FF_  = 2048;
constexpr int RFFD = 32;
constexpr int RBH  = 64;
constexpr int M_   = B_ * LP1;     // 1026
constexpr float EPS_ = 1e-5f;

// ws layout (floats), overlays:
//   z   [M*D]      (reused as h2 after qkv GEMM)
//   x1  [M*D]
//   qkv [M*3D]     (qkv+kT region reused as hact [M*FF] in FF phase)
//   kT  [B*D*LP1]
//   a   [M*D]
constexpr size_t OFFZ   = 0;
constexpr size_t OFFX1  = OFFZ  + (size_t)M_ * D_;          // 525,312
constexpr size_t OFFQKV = OFFX1 + (size_t)M_ * D_;          // 1,050,624
constexpr size_t OFFKT  = OFFQKV + (size_t)M_ * 3 * D_;     // 2,626,560
constexpr size_t OFFA   = OFFKT + (size_t)B_ * D_ * LP1;    // 3,151,872
// total = 3,677,184 floats = 14.7 MB

__device__ __forceinline__ float gelu_exact(float x) {
    return 0.5f * x * (1.0f + erff(x * 0.70710678118654752f));
}

// ---------------- LayerNorm: one block (256) per token ----------------
__global__ void k_ln(const float* __restrict__ x, const float* __restrict__ g,
                     const float* __restrict__ be, float* __restrict__ out) {
    const int m = blockIdx.x;
    const int t = threadIdx.x;
    __shared__ float red[256];
    const float v0 = x[(size_t)m * D_ + t];
    const float v1 = x[(size_t)m * D_ + t + 256];
    red[t] = v0 + v1;
    __syncthreads();
    for (int off = 128; off > 0; off >>= 1) {
        if (t < off) red[t] += red[t + off];
        __syncthreads();
    }
    const float mu = red[0] * (1.0f / D_);
    __syncthreads();
    const float d0 = v0 - mu, d1 = v1 - mu;
    red[t] = d0 * d0 + d1 * d1;
    __syncthreads();
    for (int off = 128; off > 0; off >>= 1) {
        if (t < off) red[t] += red[t + off];
        __syncthreads();
    }
    const float rstd = rsqrtf(red[0] * (1.0f / D_) + EPS_);
    out[(size_t)m * D_ + t]       = d0 * rstd * g[t]       + be[t];
    out[(size_t)m * D_ + t + 256] = d1 * rstd * g[t + 256] + be[t + 256];
}

// ---------------- tiled f32 GEMM: C[M][N] = act(A[M][K] @ W[N][K]^T + b) (+res) ----
// BM=BN=64, BK=16, 256 threads, 4x4 accum per thread. N,K multiples of 64/16; M guarded.
template <int ACT, bool RES>
__global__ __launch_bounds__(256)
void k_gemm_t(const float* __restrict__ A, const float* __restrict__ W,
              const float* __restrict__ bias, const float* __restrict__ res,
              float* __restrict__ C, int M, int N, int K) {
    constexpr int BM = 64, BN = 64, BK = 16;
    __shared__ float As[BK][BM + 4];   // +4 keeps float4 alignment & breaks conflicts
    __shared__ float Bs[BK][BN + 4];
    const int t  = threadIdx.x;
    const int tx = t & 15;
    const int ty = t >> 4;
    const int m0 = blockIdx.y * BM;
    const int n0 = blockIdx.x * BN;
    const int lr = t >> 2;   // loader row 0..63
    const int lf = t & 3;    // loader float4 0..3
    float acc[4][4] = {};

    for (int k0 = 0; k0 < K; k0 += BK) {
        {
            const int gm = m0 + lr;
            float4 v = make_float4(0.f, 0.f, 0.f, 0.f);
            if (gm < M) v = *(const float4*)&A[(size_t)gm * K + k0 + lf * 4];
            As[lf * 4 + 0][lr] = v.x; As[lf * 4 + 1][lr] = v.y;
            As[lf * 4 + 2][lr] = v.z; As[lf * 4 + 3][lr] = v.w;
        }
        {
            const int gn = n0 + lr;
            float4 v = *(const float4*)&W[(size_t)gn * K + k0 + lf * 4];
            Bs[lf * 4 + 0][lr] = v.x; Bs[lf * 4 + 1][lr] = v.y;
            Bs[lf * 4 + 2][lr] = v.z; Bs[lf * 4 + 3][lr] = v.w;
        }
        __syncthreads();
        #pragma unroll
        for (int k = 0; k < BK; ++k) {
            const float4 av = *(const float4*)&As[k][ty * 4];
            const float4 bv = *(const float4*)&Bs[k][tx * 4];
            const float am[4] = {av.x, av.y, av.z, av.w};
            const float bn[4] = {bv.x, bv.y, bv.z, bv.w};
            #pragma unroll
            for (int i = 0; i < 4; ++i)
                #pragma unroll
                for (int j = 0; j < 4; ++j) acc[i][j] += am[i] * bn[j];
        }
        __syncthreads();
    }

    const float4 bb = *(const float4*)&bias[n0 + tx * 4];
    const float bv[4] = {bb.x, bb.y, bb.z, bb.w};
    #pragma unroll
    for (int i = 0; i < 4; ++i) {
        const int gm = m0 + ty * 4 + i;
        if (gm < M) {
            float4 o;
            float* op = (float*)&o;
            #pragma unroll
            for (int j = 0; j < 4; ++j) {
                float v = acc[i][j] + bv[j];
                if (ACT == 1) v = gelu_exact(v);
                op[j] = v;
            }
            if (RES) {
                const float4 r = *(const float4*)&res[(size_t)gm * N + n0 + tx * 4];
                o.x += r.x; o.y += r.y; o.z += r.z; o.w += r.w;
            }
            *(float4*)&C[(size_t)gm * N + n0 + tx * 4] = o;
        }
    }
}

// ---------------- kT[b][d][j] = qkv[b][j][D + d]  (32x32 LDS tiles) ----------------
__global__ void k_kT(const float* __restrict__ qkv, float* __restrict__ kT) {
    __shared__ float tile[32][33];
    const int b  = blockIdx.z;
    const int j0 = blockIdx.x * 32;
    const int d0 = blockIdx.y * 32;
    const int tx = threadIdx.x;        // 32
    const int ty = threadIdx.y;        // 8
    #pragma unroll
    for (int q = 0; q < 4; ++q) {
        const int j = j0 + ty + q * 8;
        if (j < LP1)
            tile[ty + q * 8][tx] = qkv[((size_t)(b * LP1 + j)) * (3 * D_) + D_ + d0 + tx];
    }
    __syncthreads();
    #pragma unroll
    for (int q = 0; q < 4; ++q) {
        const int j = j0 + tx;
        const int d = d0 + ty + q * 8;
        if (j < LP1)
            kT[((size_t)b * D_ + d) * LP1 + j] = tile[tx][ty + q * 8];
    }
}

// ---------------- fused attention core: bias MLP + scores + softmax + PV -> a ------
// one block (256) per query token m=(b,i)
__global__ __launch_bounds__(256)
void k_attn(const float* __restrict__ qkv, const float* __restrict__ kT,
            const float* __restrict__ s_norm, const float* __restrict__ rff,
            const float* __restrict__ w1, const float* __restrict__ b1,
            const float* __restrict__ w2, const float* __restrict__ b2,
            float* __restrict__ a) {
    const int m = blockIdx.x;
    const int b = m / LP1;
    const int i = m % LP1;
    const int t = threadIdx.x;
    __shared__ float q_s[D_];
    __shared__ float p_s[H_][LP1 + 3];

    q_s[t]       = qkv[(size_t)m * (3 * D_) + t];
    q_s[t + 256] = qkv[(size_t)m * (3 * D_) + t + 256];
    const float s_i = (i == 0) ? 0.f : s_norm[b * L_ + i - 1];
    __syncthreads();

    // scores: p_s[h][j] = biasMLP(s_i - s_j)[h] + (q_h . k_h)/8
    for (int j = t; j < LP1; j += 256) {
        const float s_j = (j == 0) ? 0.f : s_norm[b * L_ + j - 1];
        const float ds = s_i - s_j;
        float feat[RFFD];
        #pragma unroll
        for (int k2 = 0; k2 < RFFD; ++k2) feat[k2] = __sinf(ds * rff[k2]);
        float bh[H_];
        #pragma unroll
        for (int h = 0; h < H_; ++h) bh[h] = b2[h];
        for (int l = 0; l < RBH; ++l) {
            float acc2 = b1[l];
            #pragma unroll
            for (int k2 = 0; k2 < RFFD; ++k2) acc2 += feat[k2] * w1[l * RFFD + k2];
            const float gl = gelu_exact(acc2);
            #pragma unroll
            for (int h = 0; h < H_; ++h) bh[h] += gl * w2[h * RBH + l];
        }
        const float* ktb = kT + (size_t)b * D_ * LP1 + j;
        #pragma unroll
        for (int h = 0; h < H_; ++h) {
            float dot = 0.f;
            #pragma unroll 8
            for (int dd = 0; dd < HD_; ++dd)
                dot += q_s[h * HD_ + dd] * ktb[(size_t)(h * HD_ + dd) * LP1];
            p_s[h][j] = bh[h] + 0.125f * dot;
        }
    }
    __syncthreads();

    // softmax: 8 parallel 32-lane groups, one head each (no __syncthreads inside)
    {
        const int g  = t >> 5;
        const int sl = t & 31;
        float mx = -1e30f;
        for (int j = sl; j < LP1; j += 32) mx = fmaxf(mx, p_s[g][j]);
        #pragma unroll
        for (int off = 16; off > 0; off >>= 1) mx = fmaxf(mx, __shfl_xor(mx, off, 32));
        float sum = 0.f;
        for (int j = sl; j < LP1; j += 32) {
            const float e = __expf(p_s[g][j] - mx);
            p_s[g][j] = e;
            sum += e;
        }
        #pragma unroll
        for (int off = 16; off > 0; off >>= 1) sum += __shfl_xor(sum, off, 32);
        const float inv = 1.0f / sum;
        for (int j = sl; j < LP1; j += 32) p_s[g][j] *= inv;
    }
    __syncthreads();

    // PV: a[m,e] = sum_j p[h(e)][j] * v[b,j,e]  (coalesced v reads)
    const float* vbase = qkv + (size_t)(b * LP1) * (3 * D_) + 2 * D_;
    for (int e = t; e < D_; e += 256) {
        const int h = e >> 6;
        float acc2 = 0.f;
        for (int j = 0; j < LP1; ++j) acc2 += p_s[h][j] * vbase[(size_t)j * (3 * D_) + e];
        a[(size_t)m * D_ + e] = acc2;
    }
}

extern "C" void kernel_launch(void* const* d_in, const int* in_sizes, int n_in,
                              void* d_out, int out_size, void* d_ws, size_t ws_size,
                              hipStream_t stream) {
    const float* x      = (const float*)d_in[0];
    const float* s_norm = (const float*)d_in[1];
    const float* rff    = (const float*)d_in[2];
    const float* rb_w1  = (const float*)d_in[3];
    const float* rb_b1  = (const float*)d_in[4];
    const float* rb_w2  = (const float*)d_in[5];
    const float* rb_b2  = (const float*)d_in[6];
    const float* n1_g   = (const float*)d_in[7];
    const float* n1_b   = (const float*)d_in[8];
    const float* n2_g   = (const float*)d_in[9];
    const float* n2_b   = (const float*)d_in[10];
    const float* in_w   = (const float*)d_in[11];
    const float* in_b   = (const float*)d_in[12];
    const float* out_w  = (const float*)d_in[13];
    const float* out_b  = (const float*)d_in[14];
    const float* ff_w1  = (const float*)d_in[15];
    const float* ff_b1  = (const float*)d_in[16];
    const float* ff_w2  = (const float*)d_in[17];
    const float* ff_b2  = (const float*)d_in[18];

    float* ws   = (float*)d_ws;
    float* z    = ws + OFFZ;      // reused as h2
    float* x1   = ws + OFFX1;
    float* qkv  = ws + OFFQKV;
    float* kT   = ws + OFFKT;
    float* a    = ws + OFFA;
    float* h2   = z;
    float* hact = qkv;            // overlays qkv+kT (both dead by FF phase)

    // 1) LN1 -> z
    k_ln<<<M_, 256, 0, stream>>>(x, n1_g, n1_b, z);
    // 2) qkv = z @ in_w^T + in_b
    k_gemm_t<0, false><<<dim3(3 * D_ / 64, (M_ + 63) / 64), 256, 0, stream>>>(
        z, in_w, in_b, nullptr, qkv, M_, 3 * D_, D_);
    // 3) kT = transpose of K part
    k_kT<<<dim3((LP1 + 31) / 32, D_ / 32, B_), dim3(32, 8), 0, stream>>>(qkv, kT);
    // 4) attention core -> a
    k_attn<<<M_, 256, 0, stream>>>(qkv, kT, s_norm, rff, rb_w1, rb_b1, rb_w2, rb_b2, a);
    // 5) x1 = x + a @ out_w^T + out_b
    k_gemm_t<0, true><<<dim3(D_ / 64, (M_ + 63) / 64), 256, 0, stream>>>(
        a, out_w, out_b, x, x1, M_, D_, D_);
    // 6) LN2 -> h2
    k_ln<<<M_, 256, 0, stream>>>(x1, n2_g, n2_b, h2);
    // 7) hact = gelu(h2 @ ff_w1^T + ff_b1)
    k_gemm_t<1, false><<<dim3(FF_ / 64, (M_ + 63) / 64), 256, 0, stream>>>(
        h2, ff_w1, ff_b1, nullptr, hact, M_, FF_, D_);
    // 8) out = x1 + hact @ ff_w2^T + ff_b2
    k_gemm_t<0, true><<<dim3(D_ / 64, (M_ + 63) / 64), 256, 0, stream>>>(
        hact, ff_w2, ff_b2, x1, (float*)d_out, M_, D_, FF_);
}